// Round 1
// baseline (4105.405 us; speedup 1.0000x reference)
//
#include <hip/hip_runtime.h>

// LSTM_88776974008866: bidirectional LSTM (B=2048, S=128, H=512, in=4) + 4 sigmoid heads.
// Strategy: per-timestep fused GEMM+cell kernel, bf16 MFMA 16x16x32, fp32 state c.
// Gate-permuted Whh layout makes the LSTM cell update lane-local in the MFMA D-fragment.

typedef __attribute__((ext_vector_type(8))) __bf16 bf16x8;
typedef __attribute__((ext_vector_type(4))) float f32x4;
typedef __attribute__((ext_vector_type(8))) unsigned short u16x8;

__device__ __forceinline__ unsigned short f2bf(float f) {
  unsigned u = __float_as_uint(f);
  u += 0x7fffu + ((u >> 16) & 1u);   // round-to-nearest-even
  return (unsigned short)(u >> 16);
}
__device__ __forceinline__ float bf2f(unsigned short s) {
  return __uint_as_float(((unsigned)s) << 16);
}
__device__ __forceinline__ float sigm(float x) { return 1.0f / (1.0f + __expf(-x)); }
__device__ __forceinline__ float tanhfast(float x) {
  float e = __expf(-2.0f * fabsf(x));
  float t = (1.0f - e) / (1.0f + e);
  return x < 0.0f ? -t : t;
}

__device__ __forceinline__ void gl_lds16(const void* g, void* l) {
  __builtin_amdgcn_global_load_lds(
      (const __attribute__((address_space(1))) unsigned int*)g,
      (__attribute__((address_space(3))) unsigned int*)l, 16, 0, 0);
}

// ---------------------------------------------------------------------------
// prep: convert Whh (fp32 [2048][512]) -> permuted bf16 Wp, and build per-row
// input-weight float4 + fused bias arrays. Permuted row r = (j>>4)*64 + gate*16 + (j&15).
// ---------------------------------------------------------------------------
__global__ __launch_bounds__(256) void prep_k(
    const float* __restrict__ Wf_hh, const float* __restrict__ Wf_ih,
    const float* __restrict__ bf_ih, const float* __restrict__ bf_hh,
    const float* __restrict__ Wb_hh, const float* __restrict__ Wb_ih,
    const float* __restrict__ bb_ih, const float* __restrict__ bb_hh,
    unsigned short* __restrict__ Wp, float4* __restrict__ wihp,
    float* __restrict__ biasp)
{
  int flat = blockIdx.x * 256 + threadIdx.x;   // 0 .. 2*2048*64-1
  int dir = flat >> 17;                        // 2048*64 = 1<<17
  int rem = flat & 131071;
  int r = rem >> 6;
  int c8 = rem & 63;
  const float* Whh = dir ? Wb_hh : Wf_hh;
  const float* Wih = dir ? Wb_ih : Wf_ih;
  const float* bih = dir ? bb_ih : bf_ih;
  const float* bhh = dir ? bb_hh : bf_hh;
  int j = ((r >> 6) << 4) | (r & 15);
  int gate = (r >> 4) & 3;
  int orig = gate * 512 + j;
  const float4* src = (const float4*)(Whh + (size_t)orig * 512 + c8 * 8);
  float4 a = src[0], b = src[1];
  u16x8 o;
  o[0] = f2bf(a.x); o[1] = f2bf(a.y); o[2] = f2bf(a.z); o[3] = f2bf(a.w);
  o[4] = f2bf(b.x); o[5] = f2bf(b.y); o[6] = f2bf(b.z); o[7] = f2bf(b.w);
  *(u16x8*)(Wp + ((size_t)dir << 20) + (size_t)r * 512 + c8 * 8) = o;
  if (c8 == 0) {
    wihp[(dir << 11) + r] = make_float4(Wih[orig * 4 + 0], Wih[orig * 4 + 1],
                                        Wih[orig * 4 + 2], Wih[orig * 4 + 3]);
    biasp[(dir << 11) + r] = bih[orig] + bhh[orig];
  }
}

// ---------------------------------------------------------------------------
// One LSTM timestep for BOTH directions. Grid: 512 blocks (256 fwd + 256 bwd),
// 256 threads. Block = 128 batch x 128 permuted-gate cols (=32 j). Fused
// GEMM (K=512) + input contribution + cell update. h double-buffered bf16.
// ---------------------------------------------------------------------------
__global__ __launch_bounds__(256) void lstm_step(
    const float* __restrict__ y,
    const unsigned short* __restrict__ Wp,
    const float4* __restrict__ wihp,
    const float* __restrict__ biasp,
    const unsigned short* __restrict__ hf_in, unsigned short* __restrict__ hf_out,
    const unsigned short* __restrict__ hb_in, unsigned short* __restrict__ hb_out,
    float* __restrict__ c_f, float* __restrict__ c_b,
    int t)
{
  __shared__ alignas(16) unsigned short As[128][64];
  __shared__ alignas(16) unsigned short Bs[128][64];
  const int tid = threadIdx.x;
  const int w = tid >> 6, lane = tid & 63;
  const int bid = blockIdx.x;
  const int dir = bid >> 8;
  const int within = bid & 255;
  const int bm0 = (within & 15) << 7;
  const int bni = within >> 4;
  const int bn0 = bni << 7;

  const unsigned short* hin = dir ? hb_in : hf_in;
  unsigned short* hout = dir ? hb_out : hf_out;
  float* cc = dir ? c_b : c_f;
  const unsigned short* W = Wp + ((size_t)dir << 20);
  const float4* wih = wihp + (dir << 11);
  const float* bias = biasp + (dir << 11);
  const int t_eff = dir ? (127 - t) : t;

  f32x4 acc[4][4];
#pragma unroll
  for (int i = 0; i < 4; ++i)
#pragma unroll
    for (int jx = 0; jx < 4; ++jx) acc[i][jx] = (f32x4){0.f, 0.f, 0.f, 0.f};

  // staging geometry: per issue, 32 rows x 64 k; lane dest = base + lane*16B
  const int srow = (w << 3) + (lane >> 3);
  const int scol = (lane & 7) << 3;
  const unsigned short* gA = hin + (size_t)(bm0 + srow) * 512 + scol;
  const unsigned short* gB = W + (size_t)(bn0 + srow) * 512 + scol;
  unsigned short* lA = &As[(w << 3)][0];
  unsigned short* lB = &Bs[(w << 3)][0];

  const int wm = w >> 1, wn = w & 1;
  const int mbase = (wm << 6) + (lane & 15);
  const int nbase = (wn << 6) + (lane & 15);

  for (int kt = 0; kt < 8; ++kt) {
    const int k0 = kt << 6;
#pragma unroll
    for (int is = 0; is < 4; ++is) {
      gl_lds16(gA + (size_t)(is * 32) * 512 + k0, lA + is * 32 * 64);
      gl_lds16(gB + (size_t)(is * 32) * 512 + k0, lB + is * 32 * 64);
    }
    __syncthreads();
#pragma unroll
    for (int ks = 0; ks < 2; ++ks) {
      const int krd = (ks << 5) + ((lane >> 4) << 3);
      bf16x8 av[4], bvv[4];
#pragma unroll
      for (int mf = 0; mf < 4; ++mf) av[mf] = *(const bf16x8*)&As[mbase + mf * 16][krd];
#pragma unroll
      for (int nf = 0; nf < 4; ++nf) bvv[nf] = *(const bf16x8*)&Bs[nbase + nf * 16][krd];
#pragma unroll
      for (int mf = 0; mf < 4; ++mf)
#pragma unroll
        for (int nf = 0; nf < 4; ++nf)
          acc[mf][nf] = __builtin_amdgcn_mfma_f32_16x16x32_bf16(av[mf], bvv[nf], acc[mf][nf], 0, 0, 0);
    }
    __syncthreads();
  }

  // Epilogue: lane-local LSTM cell update. acc[mf][gate][r]:
  //   batch b = bm0 + wm*64 + mf*16 + (lane>>4)*4 + r,  j = bni*32 + wn*16 + (lane&15)
  const int jj = lane & 15;
  const int j = (bni << 5) + (wn << 4) + jj;
  float4 wv[4]; float bv4[4];
#pragma unroll
  for (int g4 = 0; g4 < 4; ++g4) {
    int n = bn0 + (wn << 6) + (g4 << 4) + jj;
    wv[g4] = wih[n];
    bv4[g4] = bias[n];
  }
  const float4* y4 = (const float4*)y;
#pragma unroll
  for (int mf = 0; mf < 4; ++mf) {
#pragma unroll
    for (int r = 0; r < 4; ++r) {
      const int b = bm0 + (wm << 6) + (mf << 4) + ((lane >> 4) << 2) + r;
      float4 x4 = y4[(size_t)b * 128 + t_eff];
      float pre[4];
#pragma unroll
      for (int g4 = 0; g4 < 4; ++g4)
        pre[g4] = acc[mf][g4][r] + bv4[g4] + x4.x * wv[g4].x + x4.y * wv[g4].y
                 + x4.z * wv[g4].z + x4.w * wv[g4].w;
      const float ig = sigm(pre[0]);
      const float fg = sigm(pre[1]);
      const float gg = tanhfast(pre[2]);
      const float og = sigm(pre[3]);
      const size_t idx = ((size_t)b << 9) + j;
      const float cn = fg * cc[idx] + ig * gg;
      cc[idx] = cn;
      hout[idx] = f2bf(og * tanhfast(cn));
    }
  }
}

// ---------------------------------------------------------------------------
// heads: out[b][k] = sigmoid(hf[b]·Wk[0:512] + hb[b]·Wk[512:1024] + bk)
// ---------------------------------------------------------------------------
__global__ __launch_bounds__(256) void heads_k(
    const unsigned short* __restrict__ hf, const unsigned short* __restrict__ hb,
    const float* __restrict__ W1, const float* __restrict__ b1,
    const float* __restrict__ W2, const float* __restrict__ b2,
    const float* __restrict__ W3, const float* __restrict__ b3,
    const float* __restrict__ W4, const float* __restrict__ b4,
    float* __restrict__ out)
{
  const int wid = threadIdx.x >> 6, lane = threadIdx.x & 63;
  const int b = blockIdx.x * 4 + wid;
  const unsigned short* src = (lane < 32) ? (hf + ((size_t)b << 9) + (lane << 4))
                                          : (hb + ((size_t)b << 9) + ((lane - 32) << 4));
  const int woff = lane << 4;
  u16x8 v0 = *(const u16x8*)src;
  u16x8 v1 = *(const u16x8*)(src + 8);
  float hv[16];
#pragma unroll
  for (int e = 0; e < 8; ++e) { hv[e] = bf2f(v0[e]); hv[8 + e] = bf2f(v1[e]); }
  float s0 = 0.f, s1 = 0.f, s2 = 0.f, s3 = 0.f;
#pragma unroll
  for (int e = 0; e < 16; ++e) {
    float h = hv[e];
    s0 += h * W1[woff + e];
    s1 += h * W2[woff + e];
    s2 += h * W3[woff + e];
    s3 += h * W4[woff + e];
  }
#pragma unroll
  for (int off = 32; off >= 1; off >>= 1) {
    s0 += __shfl_xor(s0, off, 64);
    s1 += __shfl_xor(s1, off, 64);
    s2 += __shfl_xor(s2, off, 64);
    s3 += __shfl_xor(s3, off, 64);
  }
  if (lane == 0) {
    out[b * 4 + 0] = sigm(s0 + b1[0]);
    out[b * 4 + 1] = sigm(s1 + b2[0]);
    out[b * 4 + 2] = sigm(s2 + b3[0]);
    out[b * 4 + 3] = sigm(s3 + b4[0]);
  }
}

// ---------------------------------------------------------------------------
extern "C" void kernel_launch(void* const* d_in, const int* in_sizes, int n_in,
                              void* d_out, int out_size, void* d_ws, size_t ws_size,
                              hipStream_t stream) {
  (void)in_sizes; (void)n_in; (void)out_size; (void)ws_size;
  const float* y     = (const float*)d_in[0];
  const float* Wf_ih = (const float*)d_in[1];
  const float* Wf_hh = (const float*)d_in[2];
  const float* bf_ih = (const float*)d_in[3];
  const float* bf_hh = (const float*)d_in[4];
  const float* Wb_ih = (const float*)d_in[5];
  const float* Wb_hh = (const float*)d_in[6];
  const float* bb_ih = (const float*)d_in[7];
  const float* bb_hh = (const float*)d_in[8];
  const float* W1 = (const float*)d_in[9];  const float* b1 = (const float*)d_in[10];
  const float* W2 = (const float*)d_in[11]; const float* b2 = (const float*)d_in[12];
  const float* W3 = (const float*)d_in[13]; const float* b3 = (const float*)d_in[14];
  const float* W4 = (const float*)d_in[15]; const float* b4 = (const float*)d_in[16];

  char* ws = (char*)d_ws;
  const size_t MB = 1ull << 20;
  unsigned short* Wp  = (unsigned short*)(ws);            // 2 dirs x 2MB bf16, permuted
  unsigned short* hf0 = (unsigned short*)(ws + 4 * MB);   // 2MB
  unsigned short* hb0 = (unsigned short*)(ws + 6 * MB);   // 2MB
  float* c_f          = (float*)(ws + 8 * MB);            // 4MB
  float* c_b          = (float*)(ws + 12 * MB);           // 4MB
  unsigned short* hf1 = (unsigned short*)(ws + 16 * MB);  // 2MB
  unsigned short* hb1 = (unsigned short*)(ws + 18 * MB);  // 2MB
  float4* wihp        = (float4*)(ws + 20 * MB);          // 64KB
  float* biasp        = (float*)(ws + 20 * MB + 128 * 1024); // 16KB

  // zero h(t=0) and c for both directions (hf0,hb0,c_f,c_b are contiguous)
  hipMemsetAsync(ws + 4 * MB, 0, 12 * MB, stream);
  prep_k<<<1024, 256, 0, stream>>>(Wf_hh, Wf_ih, bf_ih, bf_hh,
                                   Wb_hh, Wb_ih, bb_ih, bb_hh,
                                   Wp, wihp, biasp);
  unsigned short* hfb[2] = {hf0, hf1};
  unsigned short* hbb[2] = {hb0, hb1};
  for (int t = 0; t < 128; ++t) {
    lstm_step<<<512, 256, 0, stream>>>(y, Wp, wihp, biasp,
        hfb[t & 1], hfb[(t + 1) & 1], hbb[t & 1], hbb[(t + 1) & 1],
        c_f, c_b, t);
  }
  // final h is in buffer 0 for both directions (128 steps, even)
  heads_k<<<512, 256, 0, stream>>>(hf0, hb0, W1, b1, W2, b2, W3, b3, W4, b4,
                                   (float*)d_out);
}